// Round 10
// baseline (28.625 us; speedup 1.0000x reference)
//
#include <hip/hip_runtime.h>

// QuantumTextClassifier: embed+PE -> 4x {q=cumprod(cos(x)); x=LN(x+q); x=LN(x+q)}
// -> mean over T -> @W + b.
// Mapping: FOUR rows per wave (16 lanes/row, 8 elems/lane = 4x float2);
// each wave runs 2 independent token-chains (A,B).
// KEY CHANGE (r10): LN params live in LDS (conflict-free [arr][blk][j][sub]
// v2f layout -> ds_read_b64 hits all 32 banks exactly once per 16-lane group,
// rows broadcast). VGPR drops ~128 -> ~60 => __launch_bounds__(256,8):
// 8 waves/SIMD resident (2x the old 4) to hide the serial DPP/trans chain.
// Pooling: per-block LDS reduce -> disjoint partial row in d_ws (no atomics).

#define NBLK 4
#define E_DIM 128
#define T_LEN 2048
#define B_SZ 32
#define C_CLS 4
#define LN_EPS 1e-5f
#define WG_PER_B 64                         // workgroups per batch element
#define WAVES_PER_WG 4
#define NUM_WG (B_SZ * WG_PER_B)            // 2048

#define F_ONE 0x3F800000                    // bit pattern of 1.0f

typedef float v2f __attribute__((ext_vector_type(2)));
typedef float v4f __attribute__((ext_vector_type(4)));

// DPP move with old-value semantics (invalid/masked lanes -> OLD bits).
template <int CTRL, int RMASK, int OLDBITS>
__device__ __forceinline__ float dppf(float v) {
    return __int_as_float(__builtin_amdgcn_update_dpp(
        OLDBITS, __float_as_int(v), CTRL, RMASK, 0xF, false));
}

// Fused-add DPP step (bound_ctrl=1: invalid lanes contribute 0).
template <int CTRL>
__device__ __forceinline__ float dpp_add(float s) {
    return s + __int_as_float(__builtin_amdgcn_update_dpp(
        0, __float_as_int(s), CTRL, 0xF, 0xF, true));
}

// Sum over each 16-lane row; result broadcast to every lane of the row.
__device__ __forceinline__ float row16_sum(float s) {
    s = dpp_add<0xB1>(s);    // quad_perm [1,0,3,2]  ~ xor1
    s = dpp_add<0x4E>(s);    // quad_perm [2,3,0,1]  ~ xor2
    s = dpp_add<0x141>(s);   // row_half_mirror      ~ xor4
    s = dpp_add<0x140>(s);   // row_mirror           ~ xor8
    return s;
}

__device__ __forceinline__ v4f ld4(const float* p) {
    return *reinterpret_cast<const v4f*>(p);
}

// cumprod(cos(X)) along the 128-elem row (16 lanes x 4 v2f): Q = prefix prods.
__device__ __forceinline__ void cumq_v(const v2f* __restrict__ X,
                                       v2f* __restrict__ Q) {
    const float c0 = __cosf(X[0].x), c1 = __cosf(X[0].y);
    const float c2 = __cosf(X[1].x), c3 = __cosf(X[1].y);
    const float c4 = __cosf(X[2].x), c5 = __cosf(X[2].y);
    const float c6 = __cosf(X[3].x), c7 = __cosf(X[3].y);
    const float p23 = c2 * c3, p45 = c4 * c5, p67 = c6 * c7;
    const float P2 = c0 * c1;
    const float P4 = P2 * p23;
    const float P6 = P4 * p45;
    const float P8 = P6 * p67;         // lane's 8-elem product
    const float P3 = P2 * c2;
    const float P5 = P4 * c4;
    const float P7 = P6 * c6;
    float sc = P8;                     // inclusive scan over 16 lanes
    sc *= dppf<0x111, 0xF, F_ONE>(sc); // row_shr:1
    sc *= dppf<0x112, 0xF, F_ONE>(sc); // row_shr:2
    sc *= dppf<0x114, 0xF, F_ONE>(sc); // row_shr:4
    sc *= dppf<0x118, 0xF, F_ONE>(sc); // row_shr:8
    // exclusive: shift by 1; row-head lanes auto-get old=1.0
    const float ex = dppf<0x111, 0xF, F_ONE>(sc);
    const v2f exv = {ex, ex};
    Q[0] = exv * (v2f){c0, P2};
    Q[1] = exv * (v2f){P3, P4};
    Q[2] = exv * (v2f){P5, P6};
    Q[3] = exv * (v2f){P7, P8};
}

// LayerNorm over a 128-elem row held as 16 lanes x 4 float2.
// g/be point into LDS at [blk][0][sub]; j-slots are 16 v2f apart.
__device__ __forceinline__ void ln8v(const v2f* __restrict__ Y,
                                     const v2f* __restrict__ g,
                                     const v2f* __restrict__ be,
                                     v2f* __restrict__ o) {
    v2f sv = (Y[0] + Y[1]) + (Y[2] + Y[3]);
    v2f qv = Y[0] * Y[0];
    qv = __builtin_elementwise_fma(Y[1], Y[1], qv);
    qv = __builtin_elementwise_fma(Y[2], Y[2], qv);
    qv = __builtin_elementwise_fma(Y[3], Y[3], qv);
    const float S  = row16_sum(sv.x + sv.y);
    const float S2 = row16_sum(qv.x + qv.y);
    const float mu  = S * (1.0f / 128.0f);
    const float var = fmaf(S2, 1.0f / 128.0f, -mu * mu);
    const float r   = rsqrtf(var + LN_EPS);
    const v2f muv = {mu, mu};
    const v2f rv  = {r, r};
    #pragma unroll
    for (int j = 0; j < 4; ++j)
        o[j] = __builtin_elementwise_fma((Y[j] - muv) * rv, g[j * 16], be[j * 16]);
}

template <bool ATOMIC>
__global__ __launch_bounds__(256, 8) void qtc_main(
    const int*   __restrict__ tokens,   // [B, T]
    const float* __restrict__ emb,      // [V, E]
    const float* __restrict__ g1,       // [NBLK, E]
    const float* __restrict__ b1,
    const float* __restrict__ g2,
    const float* __restrict__ b2,
    float*       __restrict__ outp)     // ATOMIC: pooled[B,E]; else part[NUM_WG,E]
{
    // P[a][i][j][sub] = array a (g1,b1,g2,b2), block i, elems (sub*8+2j, +1).
    // Lane `sub` reads byte sub*8 -> bank 2*sub: conflict-free, rows broadcast.
    __shared__ v2f   P[4][NBLK][4][16];              // 8 KB
    __shared__ float part[WAVES_PER_WG][4][E_DIM];   // 8 KB

    const int tid  = threadIdx.x;
    const int lane = tid & 63;
    const int wave = tid >> 6;
    const int b    = blockIdx.x / WG_PER_B;
    const int wgb  = blockIdx.x % WG_PER_B;
    const int row  = lane >> 4;          // which of the wave's 4 rows
    const int sub  = lane & 15;          // lane within row
    const int e0   = sub * 8;            // first of 8 contiguous elems
    const int wid  = wgb * WAVES_PER_WG + wave;     // [0, 256) within batch

    // ---- stage LN params into LDS (each thread writes one v2f per array) ----
    {
        const int i = tid >> 6;          // block index
        const int j = (tid >> 4) & 3;    // pair slot
        const int s = tid & 15;          // sub
        const int e = s * 8 + 2 * j;
        P[0][i][j][s] = (v2f){g1[i * E_DIM + e], g1[i * E_DIM + e + 1]};
        P[1][i][j][s] = (v2f){b1[i * E_DIM + e], b1[i * E_DIM + e + 1]};
        P[2][i][j][s] = (v2f){g2[i * E_DIM + e], g2[i * E_DIM + e + 1]};
        P[3][i][j][s] = (v2f){b2[i * E_DIM + e], b2[i * E_DIM + e + 1]};
    }
    __syncthreads();

    // ---- two token positions, PE computed directly ----
    const int   ta   = wid * 4 + row;          // token index A (< 1024)
    const int   tix  = b * T_LEN + ta;
    const int   tokA = tokens[tix];
    const int   tokB = tokens[tix + 1024];
    const float tfA  = (float)ta;
    const float tfB  = (float)(ta + 1024);

    v2f Xa[4], Xb[4];
    {
        const v4f a0  = ld4(&emb[tokA * E_DIM + e0]);
        const v4f a1  = ld4(&emb[tokA * E_DIM + e0 + 4]);
        const v4f b0  = ld4(&emb[tokB * E_DIM + e0]);
        const v4f b1v = ld4(&emb[tokB * E_DIM + e0 + 4]);
        const v2f ea[4] = {a0.xy, a0.zw, a1.xy, a1.zw};
        const v2f eb[4] = {b0.xy, b0.zw, b1v.xy, b1v.zw};
        #pragma unroll
        for (int j = 0; j < 4; ++j) {
            const float f = __expf(-(float)(e0 + 2 * j) * (9.210340371976184f / 128.0f));
            Xa[j] = ea[j] + (v2f){__sinf(tfA * f), __cosf(tfA * f)};
            Xb[j] = eb[j] + (v2f){__sinf(tfB * f), __cosf(tfB * f)};
        }
    }

    // ---- 4 transformer-sim blocks, two independent chains (A,B) ----
    #pragma unroll
    for (int i = 0; i < NBLK; ++i) {
        const v2f* g1p = &P[0][i][0][sub];
        const v2f* b1p = &P[1][i][0][sub];
        const v2f* g2p = &P[2][i][0][sub];
        const v2f* b2p = &P[3][i][0][sub];
        v2f Qa[4], Qb[4], Y[4];
        cumq_v(Xa, Qa);
        cumq_v(Xb, Qb);
        #pragma unroll
        for (int k = 0; k < 4; ++k) Y[k] = Xa[k] + Qa[k];
        ln8v(Y, g1p, b1p, Xa);
        #pragma unroll
        for (int k = 0; k < 4; ++k) Y[k] = Xb[k] + Qb[k];
        ln8v(Y, g1p, b1p, Xb);
        #pragma unroll
        for (int k = 0; k < 4; ++k) Y[k] = Xa[k] + Qa[k];
        ln8v(Y, g2p, b2p, Xa);
        #pragma unroll
        for (int k = 0; k < 4; ++k) Y[k] = Xb[k] + Qb[k];
        ln8v(Y, g2p, b2p, Xb);
    }

    // ---- block-level pooling ----
    const v4f lo = {Xa[0].x + Xb[0].x, Xa[0].y + Xb[0].y,
                    Xa[1].x + Xb[1].x, Xa[1].y + Xb[1].y};
    const v4f hi = {Xa[2].x + Xb[2].x, Xa[2].y + Xb[2].y,
                    Xa[3].x + Xb[3].x, Xa[3].y + Xb[3].y};
    *reinterpret_cast<v4f*>(&part[wave][row][e0])     = lo;
    *reinterpret_cast<v4f*>(&part[wave][row][e0 + 4]) = hi;
    __syncthreads();
    if (tid < E_DIM) {
        float s = 0.0f;
        #pragma unroll
        for (int w = 0; w < WAVES_PER_WG; ++w)
            #pragma unroll
            for (int r = 0; r < 4; ++r)
                s += part[w][r][tid];
        if (ATOMIC)
            atomicAdd(&outp[b * E_DIM + tid], s);
        else
            outp[blockIdx.x * E_DIM + tid] = s;   // disjoint partial row
    }
}

// Fused-add DPP over full wave (for the final reduce kernels).
__device__ __forceinline__ float wave_sum_tail(float s) {
    s = dpp_add<0xB1>(s);
    s = dpp_add<0x4E>(s);
    s = dpp_add<0x141>(s);
    s = dpp_add<0x140>(s);
    s = s + __int_as_float(__builtin_amdgcn_update_dpp(
        0, __float_as_int(s), 0x142, 0xA, 0xF, true));   // row_bcast15 -> rows 1,3
    s = s + __int_as_float(__builtin_amdgcn_update_dpp(
        0, __float_as_int(s), 0x143, 0xC, 0xF, true));   // row_bcast31 -> rows 2,3
    return s;                                            // total in lane 63
}

// Partials path: reduce 64 WG-partials per batch (w-loop split across 2 half-
// blocks of threads), then tiny matmul on wave 0.
__global__ __launch_bounds__(256) void qtc_final_p(
    const float* __restrict__ part,    // [NUM_WG, E]
    const float* __restrict__ W,       // [E, C]
    const float* __restrict__ bias,    // [C]
    float*       __restrict__ out)     // [B, C]
{
    __shared__ float red[2][E_DIM];
    __shared__ float pooled[E_DIM];
    const int b   = blockIdx.x;
    const int tid = threadIdx.x;
    const int e   = tid & 127;
    const int h   = tid >> 7;          // 0 or 1: which half of the w-range
    const float* base = part + (size_t)b * WG_PER_B * E_DIM + e;
    float s = 0.0f;
    #pragma unroll 8
    for (int w = h * 32; w < h * 32 + 32; ++w)
        s += base[w * E_DIM];
    red[h][e] = s;
    __syncthreads();
    if (tid < E_DIM)
        pooled[tid] = red[0][tid] + red[1][tid];
    __syncthreads();
    if (tid < 64) {
        const int lane = tid;
        const int e0 = 2 * lane;
        const float p0 = pooled[e0];
        const float p1 = pooled[e0 + 1];
        float acc[C_CLS];
        #pragma unroll
        for (int c = 0; c < C_CLS; ++c)
            acc[c] = fmaf(p0, W[e0 * C_CLS + c], p1 * W[(e0 + 1) * C_CLS + c]);
        #pragma unroll
        for (int c = 0; c < C_CLS; ++c)
            acc[c] = wave_sum_tail(acc[c]);
        if (lane == 63) {
            #pragma unroll
            for (int c = 0; c < C_CLS; ++c)
                out[b * C_CLS + c] = fmaf(acc[c], 1.0f / (float)T_LEN, bias[c]);
        }
    }
}

// Atomic-pooled fallback final (pooled[B,E] already summed).
__global__ __launch_bounds__(64) void qtc_final_a(
    const float* __restrict__ pooled,  // [B, E]
    const float* __restrict__ W,
    const float* __restrict__ bias,
    float*       __restrict__ out)
{
    const int b    = blockIdx.x;
    const int lane = threadIdx.x;
    const int e0   = 2 * lane;
    const float p0 = pooled[b * E_DIM + e0];
    const float p1 = pooled[b * E_DIM + e0 + 1];
    float acc[C_CLS];
    #pragma unroll
    for (int c = 0; c < C_CLS; ++c)
        acc[c] = fmaf(p0, W[e0 * C_CLS + c], p1 * W[(e0 + 1) * C_CLS + c]);
    #pragma unroll
    for (int c = 0; c < C_CLS; ++c)
        acc[c] = wave_sum_tail(acc[c]);
    if (lane == 63) {
        #pragma unroll
        for (int c = 0; c < C_CLS; ++c)
            out[b * C_CLS + c] = fmaf(acc[c], 1.0f / (float)T_LEN, bias[c]);
    }
}

extern "C" void kernel_launch(void* const* d_in, const int* in_sizes, int n_in,
                              void* d_out, int out_size, void* d_ws, size_t ws_size,
                              hipStream_t stream) {
    const int*   tokens = (const int*)  d_in[0];
    const float* emb    = (const float*)d_in[1];
    const float* g1     = (const float*)d_in[2];
    const float* b1     = (const float*)d_in[3];
    const float* g2     = (const float*)d_in[4];
    const float* b2     = (const float*)d_in[5];
    // d_in[6] = q_weights: provably unused by the reference
    const float* W      = (const float*)d_in[7];
    const float* bias   = (const float*)d_in[8];
    float* out = (float*)d_out;

    const size_t part_bytes = (size_t)NUM_WG * E_DIM * sizeof(float);  // 1 MB
    if (ws_size >= part_bytes) {
        float* part = (float*)d_ws;
        qtc_main<false><<<NUM_WG, 256, 0, stream>>>(tokens, emb, g1, b1, g2, b2, part);
        qtc_final_p<<<B_SZ, 256, 0, stream>>>(part, W, bias, out);
    } else {
        float* pooled = (float*)d_ws;  // 16 KB
        hipMemsetAsync(pooled, 0, B_SZ * E_DIM * sizeof(float), stream);
        qtc_main<true><<<NUM_WG, 256, 0, stream>>>(tokens, emb, g1, b1, g2, b2, pooled);
        qtc_final_a<<<B_SZ, 64, 0, stream>>>(pooled, W, bias, out);
    }
}

// Round 11
// 28.582 us; speedup vs baseline: 1.0015x; 1.0015x over previous
//
#include <hip/hip_runtime.h>

// QuantumTextClassifier: embed+PE -> 4x {q=cumprod(cos(x)); x=LN(x+q); x=LN(x+q)}
// -> mean over T -> @W + b.
// Mapping: FOUR rows per wave (16 lanes/row, 8 elems/lane = 4x float2);
// each wave runs 2 independent token-chains (A,B).
// KEY CHANGE (r11): chains A and B are fused at the FUNCTION level and their
// DPP steps explicitly interleaved (scan: A,B,A,B... with local-prefix muls as
// filler; LN reduce: 4 concurrent streams sA,sB,s2A,s2B -> hazard distance 3).
// Rationale: dependent DPP ops need ~2 wait states on gfx9-lineage; back-to-back
// serial DPP chains force s_nop padding that eats issue slots in every wave --
// the suspected cause of the mapping-independent ~30% issue-efficiency ceiling.
// LN params in LDS (conflict-free layout), __launch_bounds__(256,8).
// Pooling: per-block LDS reduce -> disjoint partial row in d_ws (no atomics).

#define NBLK 4
#define E_DIM 128
#define T_LEN 2048
#define B_SZ 32
#define C_CLS 4
#define LN_EPS 1e-5f
#define WG_PER_B 64                         // workgroups per batch element
#define WAVES_PER_WG 4
#define NUM_WG (B_SZ * WG_PER_B)            // 2048

#define F_ONE 0x3F800000                    // bit pattern of 1.0f

typedef float v2f __attribute__((ext_vector_type(2)));
typedef float v4f __attribute__((ext_vector_type(4)));

// DPP move with old-value semantics (invalid/masked lanes -> OLD bits).
template <int CTRL, int RMASK, int OLDBITS>
__device__ __forceinline__ float dppf(float v) {
    return __int_as_float(__builtin_amdgcn_update_dpp(
        OLDBITS, __float_as_int(v), CTRL, RMASK, 0xF, false));
}

// Fused-add DPP step (bound_ctrl=1: invalid lanes contribute 0).
template <int CTRL>
__device__ __forceinline__ float dpp_add(float s) {
    return s + __int_as_float(__builtin_amdgcn_update_dpp(
        0, __float_as_int(s), CTRL, 0xF, 0xF, true));
}

__device__ __forceinline__ v4f ld4(const float* p) {
    return *reinterpret_cast<const v4f*>(p);
}

// cumprod(cos(.)) for BOTH chains, DPP scans interleaved (A,B alternating)
// with the independent local-prefix muls placed into the hazard gaps.
__device__ __forceinline__ void cumq2(const v2f* __restrict__ Xa,
                                      const v2f* __restrict__ Xb,
                                      v2f* __restrict__ Qa,
                                      v2f* __restrict__ Qb) {
    const float a0 = __cosf(Xa[0].x), a1 = __cosf(Xa[0].y);
    const float a2 = __cosf(Xa[1].x), a3 = __cosf(Xa[1].y);
    const float a4 = __cosf(Xa[2].x), a5 = __cosf(Xa[2].y);
    const float a6 = __cosf(Xa[3].x), a7 = __cosf(Xa[3].y);
    const float b0 = __cosf(Xb[0].x), b1 = __cosf(Xb[0].y);
    const float b2 = __cosf(Xb[1].x), b3 = __cosf(Xb[1].y);
    const float b4 = __cosf(Xb[2].x), b5 = __cosf(Xb[2].y);
    const float b6 = __cosf(Xb[3].x), b7 = __cosf(Xb[3].y);
    // pair products (all independent)
    const float a01 = a0 * a1, a23 = a2 * a3, a45 = a4 * a5, a67 = a6 * a7;
    const float b01 = b0 * b1, b23 = b2 * b3, b45 = b4 * b5, b67 = b6 * b7;
    // running even prefixes
    const float PA4 = a01 * a23, PB4 = b01 * b23;
    const float PA6 = PA4 * a45, PB6 = PB4 * b45;
    const float PA8 = PA6 * a67, PB8 = PB6 * b67;
    // 16-lane inclusive scans, interleaved; odd prefixes computed in the gaps
    float scA = PA8, scB = PB8;
    scA *= dppf<0x111, 0xF, F_ONE>(scA);
    scB *= dppf<0x111, 0xF, F_ONE>(scB);
    const float PA3 = a01 * a2, PB3 = b01 * b2;
    scA *= dppf<0x112, 0xF, F_ONE>(scA);
    scB *= dppf<0x112, 0xF, F_ONE>(scB);
    const float PA5 = PA4 * a4, PB5 = PB4 * b4;
    scA *= dppf<0x114, 0xF, F_ONE>(scA);
    scB *= dppf<0x114, 0xF, F_ONE>(scB);
    const float PA7 = PA6 * a6, PB7 = PB6 * b6;
    scA *= dppf<0x118, 0xF, F_ONE>(scA);
    scB *= dppf<0x118, 0xF, F_ONE>(scB);
    // exclusive: shift by 1; row-head lanes auto-get old=1.0
    const float exA = dppf<0x111, 0xF, F_ONE>(scA);
    const float exB = dppf<0x111, 0xF, F_ONE>(scB);
    const v2f eA = {exA, exA}, eB = {exB, exB};
    Qa[0] = eA * (v2f){a0,  a01};  Qb[0] = eB * (v2f){b0,  b01};
    Qa[1] = eA * (v2f){PA3, PA4};  Qb[1] = eB * (v2f){PB3, PB4};
    Qa[2] = eA * (v2f){PA5, PA6};  Qb[2] = eB * (v2f){PB5, PB6};
    Qa[3] = eA * (v2f){PA7, PA8};  Qb[3] = eB * (v2f){PB7, PB8};
}

// LayerNorm for BOTH chains; the four reduction streams (sA, sB, s2A, s2B)
// are interleaved -> each DPP's producer is 3 instructions back (no hazards).
// g/be point into LDS at [blk][0][sub]; j-slots are 16 v2f apart.
__device__ __forceinline__ void ln8v2(const v2f* __restrict__ Ya,
                                      const v2f* __restrict__ Yb,
                                      const v2f* __restrict__ g,
                                      const v2f* __restrict__ be,
                                      v2f* __restrict__ oa,
                                      v2f* __restrict__ ob) {
    v2f svA = (Ya[0] + Ya[1]) + (Ya[2] + Ya[3]);
    v2f svB = (Yb[0] + Yb[1]) + (Yb[2] + Yb[3]);
    v2f qvA = Ya[0] * Ya[0];
    v2f qvB = Yb[0] * Yb[0];
    qvA = __builtin_elementwise_fma(Ya[1], Ya[1], qvA);
    qvB = __builtin_elementwise_fma(Yb[1], Yb[1], qvB);
    qvA = __builtin_elementwise_fma(Ya[2], Ya[2], qvA);
    qvB = __builtin_elementwise_fma(Yb[2], Yb[2], qvB);
    qvA = __builtin_elementwise_fma(Ya[3], Ya[3], qvA);
    qvB = __builtin_elementwise_fma(Yb[3], Yb[3], qvB);
    float sA  = svA.x + svA.y, sB  = svB.x + svB.y;
    float s2A = qvA.x + qvA.y, s2B = qvB.x + qvB.y;
    // interleaved 4-stream 16-lane reduction
    sA  = dpp_add<0xB1>(sA);   sB  = dpp_add<0xB1>(sB);
    s2A = dpp_add<0xB1>(s2A);  s2B = dpp_add<0xB1>(s2B);
    sA  = dpp_add<0x4E>(sA);   sB  = dpp_add<0x4E>(sB);
    s2A = dpp_add<0x4E>(s2A);  s2B = dpp_add<0x4E>(s2B);
    sA  = dpp_add<0x141>(sA);  sB  = dpp_add<0x141>(sB);
    s2A = dpp_add<0x141>(s2A); s2B = dpp_add<0x141>(s2B);
    sA  = dpp_add<0x140>(sA);  sB  = dpp_add<0x140>(sB);
    s2A = dpp_add<0x140>(s2A); s2B = dpp_add<0x140>(s2B);
    const float muA  = sA * (1.0f / 128.0f);
    const float muB  = sB * (1.0f / 128.0f);
    const float varA = fmaf(s2A, 1.0f / 128.0f, -muA * muA);
    const float varB = fmaf(s2B, 1.0f / 128.0f, -muB * muB);
    const float rA   = rsqrtf(varA + LN_EPS);
    const float rB   = rsqrtf(varB + LN_EPS);
    const v2f muAv = {muA, muA}, rAv = {rA, rA};
    const v2f muBv = {muB, muB}, rBv = {rB, rB};
    #pragma unroll
    for (int j = 0; j < 4; ++j) {
        const v2f gj = g[j * 16], bj = be[j * 16];
        oa[j] = __builtin_elementwise_fma((Ya[j] - muAv) * rAv, gj, bj);
        ob[j] = __builtin_elementwise_fma((Yb[j] - muBv) * rBv, gj, bj);
    }
}

template <bool ATOMIC>
__global__ __launch_bounds__(256, 8) void qtc_main(
    const int*   __restrict__ tokens,   // [B, T]
    const float* __restrict__ emb,      // [V, E]
    const float* __restrict__ g1,       // [NBLK, E]
    const float* __restrict__ b1,
    const float* __restrict__ g2,
    const float* __restrict__ b2,
    float*       __restrict__ outp)     // ATOMIC: pooled[B,E]; else part[NUM_WG,E]
{
    // P[a][i][j][sub]: lane `sub` reads byte sub*8 -> bank 2*sub, conflict-free.
    __shared__ v2f   P[4][NBLK][4][16];              // 8 KB
    __shared__ float part[WAVES_PER_WG][4][E_DIM];   // 8 KB

    const int tid  = threadIdx.x;
    const int lane = tid & 63;
    const int wave = tid >> 6;
    const int b    = blockIdx.x / WG_PER_B;
    const int wgb  = blockIdx.x % WG_PER_B;
    const int row  = lane >> 4;          // which of the wave's 4 rows
    const int sub  = lane & 15;          // lane within row
    const int e0   = sub * 8;            // first of 8 contiguous elems
    const int wid  = wgb * WAVES_PER_WG + wave;     // [0, 256) within batch

    // ---- stage LN params into LDS (v2f loads; each thread one v2f/array) ----
    {
        const int i = tid >> 6;          // block index
        const int j = (tid >> 4) & 3;    // pair slot
        const int s = tid & 15;          // sub
        const int e = s * 8 + 2 * j;
        P[0][i][j][s] = *reinterpret_cast<const v2f*>(&g1[i * E_DIM + e]);
        P[1][i][j][s] = *reinterpret_cast<const v2f*>(&b1[i * E_DIM + e]);
        P[2][i][j][s] = *reinterpret_cast<const v2f*>(&g2[i * E_DIM + e]);
        P[3][i][j][s] = *reinterpret_cast<const v2f*>(&b2[i * E_DIM + e]);
    }
    __syncthreads();

    // ---- two token positions, PE computed directly ----
    const int   ta   = wid * 4 + row;          // token index A (< 1024)
    const int   tix  = b * T_LEN + ta;
    const int   tokA = tokens[tix];
    const int   tokB = tokens[tix + 1024];
    const float tfA  = (float)ta;
    const float tfB  = (float)(ta + 1024);

    v2f Xa[4], Xb[4];
    {
        const v4f a0  = ld4(&emb[tokA * E_DIM + e0]);
        const v4f a1  = ld4(&emb[tokA * E_DIM + e0 + 4]);
        const v4f c0  = ld4(&emb[tokB * E_DIM + e0]);
        const v4f c1  = ld4(&emb[tokB * E_DIM + e0 + 4]);
        const v2f ea[4] = {a0.xy, a0.zw, a1.xy, a1.zw};
        const v2f eb[4] = {c0.xy, c0.zw, c1.xy, c1.zw};
        #pragma unroll
        for (int j = 0; j < 4; ++j) {
            const float f = __expf(-(float)(e0 + 2 * j) * (9.210340371976184f / 128.0f));
            Xa[j] = ea[j] + (v2f){__sinf(tfA * f), __cosf(tfA * f)};
            Xb[j] = eb[j] + (v2f){__sinf(tfB * f), __cosf(tfB * f)};
        }
    }

    // ---- 4 transformer-sim blocks, two interleaved chains (A,B) ----
    #pragma unroll
    for (int i = 0; i < NBLK; ++i) {
        const v2f* g1p = &P[0][i][0][sub];
        const v2f* b1p = &P[1][i][0][sub];
        const v2f* g2p = &P[2][i][0][sub];
        const v2f* b2p = &P[3][i][0][sub];
        v2f Qa[4], Qb[4], Ya[4], Yb[4];
        cumq2(Xa, Xb, Qa, Qb);
        #pragma unroll
        for (int k = 0; k < 4; ++k) { Ya[k] = Xa[k] + Qa[k]; Yb[k] = Xb[k] + Qb[k]; }
        ln8v2(Ya, Yb, g1p, b1p, Xa, Xb);
        #pragma unroll
        for (int k = 0; k < 4; ++k) { Ya[k] = Xa[k] + Qa[k]; Yb[k] = Xb[k] + Qb[k]; }
        ln8v2(Ya, Yb, g2p, b2p, Xa, Xb);
    }

    // ---- block-level pooling ----
    const v4f lo = {Xa[0].x + Xb[0].x, Xa[0].y + Xb[0].y,
                    Xa[1].x + Xb[1].x, Xa[1].y + Xb[1].y};
    const v4f hi = {Xa[2].x + Xb[2].x, Xa[2].y + Xb[2].y,
                    Xa[3].x + Xb[3].x, Xa[3].y + Xb[3].y};
    *reinterpret_cast<v4f*>(&part[wave][row][e0])     = lo;
    *reinterpret_cast<v4f*>(&part[wave][row][e0 + 4]) = hi;
    __syncthreads();
    if (tid < E_DIM) {
        float s = 0.0f;
        #pragma unroll
        for (int w = 0; w < WAVES_PER_WG; ++w)
            #pragma unroll
            for (int r = 0; r < 4; ++r)
                s += part[w][r][tid];
        if (ATOMIC)
            atomicAdd(&outp[b * E_DIM + tid], s);
        else
            outp[blockIdx.x * E_DIM + tid] = s;   // disjoint partial row
    }
}

// Fused-add DPP over full wave (for the final reduce kernels).
__device__ __forceinline__ float wave_sum_tail(float s) {
    s = dpp_add<0xB1>(s);
    s = dpp_add<0x4E>(s);
    s = dpp_add<0x141>(s);
    s = dpp_add<0x140>(s);
    s = s + __int_as_float(__builtin_amdgcn_update_dpp(
        0, __float_as_int(s), 0x142, 0xA, 0xF, true));   // row_bcast15 -> rows 1,3
    s = s + __int_as_float(__builtin_amdgcn_update_dpp(
        0, __float_as_int(s), 0x143, 0xC, 0xF, true));   // row_bcast31 -> rows 2,3
    return s;                                            // total in lane 63
}

// Partials path: reduce 64 WG-partials per batch (w-loop split across 2 half-
// blocks of threads), then tiny matmul on wave 0.
__global__ __launch_bounds__(256) void qtc_final_p(
    const float* __restrict__ part,    // [NUM_WG, E]
    const float* __restrict__ W,       // [E, C]
    const float* __restrict__ bias,    // [C]
    float*       __restrict__ out)     // [B, C]
{
    __shared__ float red[2][E_DIM];
    __shared__ float pooled[E_DIM];
    const int b   = blockIdx.x;
    const int tid = threadIdx.x;
    const int e   = tid & 127;
    const int h   = tid >> 7;          // 0 or 1: which half of the w-range
    const float* base = part + (size_t)b * WG_PER_B * E_DIM + e;
    float s = 0.0f;
    #pragma unroll 8
    for (int w = h * 32; w < h * 32 + 32; ++w)
        s += base[w * E_DIM];
    red[h][e] = s;
    __syncthreads();
    if (tid < E_DIM)
        pooled[tid] = red[0][tid] + red[1][tid];
    __syncthreads();
    if (tid < 64) {
        const int lane = tid;
        const int e0 = 2 * lane;
        const float p0 = pooled[e0];
        const float p1 = pooled[e0 + 1];
        float acc[C_CLS];
        #pragma unroll
        for (int c = 0; c < C_CLS; ++c)
            acc[c] = fmaf(p0, W[e0 * C_CLS + c], p1 * W[(e0 + 1) * C_CLS + c]);
        #pragma unroll
        for (int c = 0; c < C_CLS; ++c)
            acc[c] = wave_sum_tail(acc[c]);
        if (lane == 63) {
            #pragma unroll
            for (int c = 0; c < C_CLS; ++c)
                out[b * C_CLS + c] = fmaf(acc[c], 1.0f / (float)T_LEN, bias[c]);
        }
    }
}

// Atomic-pooled fallback final (pooled[B,E] already summed).
__global__ __launch_bounds__(64) void qtc_final_a(
    const float* __restrict__ pooled,  // [B, E]
    const float* __restrict__ W,
    const float* __restrict__ bias,
    float*       __restrict__ out)
{
    const int b    = blockIdx.x;
    const int lane = threadIdx.x;
    const int e0   = 2 * lane;
    const float p0 = pooled[b * E_DIM + e0];
    const float p1 = pooled[b * E_DIM + e0 + 1];
    float acc[C_CLS];
    #pragma unroll
    for (int c = 0; c < C_CLS; ++c)
        acc[c] = fmaf(p0, W[e0 * C_CLS + c], p1 * W[(e0 + 1) * C_CLS + c]);
    #pragma unroll
    for (int c = 0; c < C_CLS; ++c)
        acc[c] = wave_sum_tail(acc[c]);
    if (lane == 63) {
        #pragma unroll
        for (int c = 0; c < C_CLS; ++c)
            out[b * C_CLS + c] = fmaf(acc[c], 1.0f / (float)T_LEN, bias[c]);
    }
}

extern "C" void kernel_launch(void* const* d_in, const int* in_sizes, int n_in,
                              void* d_out, int out_size, void* d_ws, size_t ws_size,
                              hipStream_t stream) {
    const int*   tokens = (const int*)  d_in[0];
    const float* emb    = (const float*)d_in[1];
    const float* g1     = (const float*)d_in[2];
    const float* b1     = (const float*)d_in[3];
    const float* g2     = (const float*)d_in[4];
    const float* b2     = (const float*)d_in[5];
    // d_in[6] = q_weights: provably unused by the reference
    const float* W      = (const float*)d_in[7];
    const float* bias   = (const float*)d_in[8];
    float* out = (float*)d_out;

    const size_t part_bytes = (size_t)NUM_WG * E_DIM * sizeof(float);  // 1 MB
    if (ws_size >= part_bytes) {
        float* part = (float*)d_ws;
        qtc_main<false><<<NUM_WG, 256, 0, stream>>>(tokens, emb, g1, b1, g2, b2, part);
        qtc_final_p<<<B_SZ, 256, 0, stream>>>(part, W, bias, out);
    } else {
        float* pooled = (float*)d_ws;  // 16 KB
        hipMemsetAsync(pooled, 0, B_SZ * E_DIM * sizeof(float), stream);
        qtc_main<true><<<NUM_WG, 256, 0, stream>>>(tokens, emb, g1, b1, g2, b2, pooled);
        qtc_final_a<<<B_SZ, 64, 0, stream>>>(pooled, W, bias, out);
    }
}